// Round 4
// baseline (186.615 us; speedup 1.0000x reference)
//
#include <hip/hip_runtime.h>

// DiceLoss: fp32 inputs [B=16, C=3, HW=262144], scalar fp32 output.
// num[c] = 2*sum_bn(x*t); den[c] = sum_bn(x^2) + sum_bn(t^2)
// out = 1 - mean_c((num[c]+eps)/(den[c]+eps))
//
// R4: single fused kernel. Per-block partials -> ws (no atomics on data;
// R1 showed same-line atomicAdd serialization = 89us). Last block to
// finish (atomic ticket on a memset-zeroed counter) reduces all 1536
// partials and writes the scalar. Measured dur_us includes ~73us of
// harness reset (256MiB ws poison fill 41.5us + ~31us input restore).

#define HW 262144          // 512*512
#define NC 3
#define NB 16
#define NBX 32             // blocks per (b,c) plane
#define ITERS (HW / 4 / NBX / 256)   // 8 float4-pair loads per thread
#define NPART (NB * NBX)   // 512 partials per channel
#define NBLOCKS (NB * NC * NBX)      // 1536
#define EPSF 1e-5f

// ws layout: float2 part[c*NPART + b*NBX + bx]; unsigned counter at part[NBLOCKS]

__global__ __launch_bounds__(256) void dice_fused(
    const float* __restrict__ x, const float* __restrict__ t,
    float2* __restrict__ part, unsigned* __restrict__ counter,
    float* __restrict__ out) {
  const int bx = blockIdx.x;
  const int c  = blockIdx.y;
  const int b  = blockIdx.z;
  const size_t base = ((size_t)b * NC + c) * (size_t)HW;
  const float4* __restrict__ x4 = (const float4*)(x + base);
  const float4* __restrict__ t4 = (const float4*)(t + base);

  const int start = bx * (ITERS * 256) + threadIdx.x;

  float4 a[ITERS], g[ITERS];
  #pragma unroll
  for (int k = 0; k < ITERS; k++) a[k] = x4[start + k * 256];
  #pragma unroll
  for (int k = 0; k < ITERS; k++) g[k] = t4[start + k * 256];

  float s_xt = 0.f, s_den = 0.f;
  #pragma unroll
  for (int k = 0; k < ITERS; k++) {
    s_xt  += a[k].x * g[k].x + a[k].y * g[k].y + a[k].z * g[k].z + a[k].w * g[k].w;
    s_den += a[k].x * a[k].x + a[k].y * a[k].y + a[k].z * a[k].z + a[k].w * a[k].w
           + g[k].x * g[k].x + g[k].y * g[k].y + g[k].z * g[k].z + g[k].w * g[k].w;
  }

  // wave-64 shuffle reduction
  #pragma unroll
  for (int off = 32; off > 0; off >>= 1) {
    s_xt  += __shfl_down(s_xt, off);
    s_den += __shfl_down(s_den, off);
  }

  __shared__ float sm[8];
  __shared__ unsigned ticket_sm;
  const int wave = threadIdx.x >> 6;
  const int lane = threadIdx.x & 63;
  if (lane == 0) { sm[wave * 2] = s_xt; sm[wave * 2 + 1] = s_den; }
  __syncthreads();

  if (threadIdx.x == 0) {
    float2 p;
    p.x = sm[0] + sm[2] + sm[4] + sm[6];
    p.y = sm[1] + sm[3] + sm[5] + sm[7];
    part[c * NPART + b * NBX + bx] = p;
    __threadfence();                       // release: partial visible device-wide
    ticket_sm = atomicAdd(counter, 1u);    // device-scope ticket
  }
  __syncthreads();

  if (ticket_sm != NBLOCKS - 1) return;    // not the last block to finish

  // ---- last block: reduce all partials + epilogue ----
  __threadfence();                         // acquire: see all partials
  float acc = 0.f;
  for (int cc = 0; cc < NC; cc++) {
    float sx = 0.f, sd = 0.f;
    #pragma unroll
    for (int k = 0; k < NPART / 256; k++) {          // 2 iters
      float2 v = part[cc * NPART + threadIdx.x + k * 256];
      sx += v.x;
      sd += v.y;
    }
    #pragma unroll
    for (int off = 32; off > 0; off >>= 1) {
      sx += __shfl_down(sx, off);
      sd += __shfl_down(sd, off);
    }
    __syncthreads();   // sm reuse
    if (lane == 0) { sm[wave * 2] = sx; sm[wave * 2 + 1] = sd; }
    __syncthreads();
    if (threadIdx.x == 0) {
      float num = 2.f * (sm[0] + sm[2] + sm[4] + sm[6]) + EPSF;
      float den = (sm[1] + sm[3] + sm[5] + sm[7]) + EPSF;
      acc += num / den;
    }
  }
  if (threadIdx.x == 0) out[0] = 1.f - acc * (1.f / 3.f);
}

extern "C" void kernel_launch(void* const* d_in, const int* in_sizes, int n_in,
                              void* d_out, int out_size, void* d_ws, size_t ws_size,
                              hipStream_t stream) {
  const float* x = (const float*)d_in[0];
  const float* t = (const float*)d_in[1];
  float* out   = (float*)d_out;
  float2* part = (float2*)d_ws;                       // 1536 float2 = 12 KB
  unsigned* counter = (unsigned*)(part + NBLOCKS);    // 4 B, after partials

  hipMemsetAsync(counter, 0, sizeof(unsigned), stream);   // ws is 0xAA-poisoned

  dim3 grid(NBX, NC, NB);   // 1536 blocks
  dice_fused<<<grid, 256, 0, stream>>>(x, t, part, counter, out);
}

// Round 7
// 118.652 us; speedup vs baseline: 1.5728x; 1.5728x over previous
//
#include <hip/hip_runtime.h>

// DiceLoss: fp32 inputs [B=16, C=3, HW=262144], scalar fp32 output.
// num[c] = 2*sum_bn(x*t); den[c] = sum_bn(x^2) + sum_bn(t^2)
// out = 1 - mean_c((num[c]+eps)/(den[c]+eps))
//
// R6 = R5 with the nontemporal-load compile error fixed: clang's
// __builtin_nontemporal_load needs a native vector type, not HIP's
// float4 class — use ext_vector_type(4) float. Structure = R3 two-kernel
// (best: 114.7us total, ~28us ours; ~86us fixed harness reset: 41.5us
// 256MiB ws poison fill + ~31us input restore + gaps). NT loads so our
// streaming reads don't evict the L3-resident input lines mid-kernel
// (FETCH_SIZE=50MB showed half the 100.7MB read already misses to HBM).

#define HW 262144          // 512*512
#define NC 3
#define NB 16
#define NBX 32             // blocks per (b,c) plane — compile-time so loop unrolls
#define ITERS (HW / 4 / NBX / 256)   // 8 float4-pair loads per thread
#define NPART (NB * NBX)   // 512 partials per channel
#define EPSF 1e-5f

typedef float f4 __attribute__((ext_vector_type(4)));   // native vector for NT builtin

// ws layout: float2 partial[c*NPART + b*NBX + bx] = {sum(x*t), sum(x^2+t^2)}

__global__ __launch_bounds__(256) void dice_partials(
    const float* __restrict__ x, const float* __restrict__ t,
    float2* __restrict__ part) {
  const int bx = blockIdx.x;
  const int c  = blockIdx.y;
  const int b  = blockIdx.z;
  const size_t base = ((size_t)b * NC + c) * (size_t)HW;
  const f4* __restrict__ x4 = (const f4*)(x + base);
  const f4* __restrict__ t4 = (const f4*)(t + base);

  const int start = bx * (ITERS * 256) + threadIdx.x;

  // All loads issued up front (MLP), nontemporal so we don't evict the
  // L3-resident input halves we haven't read yet.
  f4 a[ITERS], g[ITERS];
  #pragma unroll
  for (int k = 0; k < ITERS; k++) a[k] = __builtin_nontemporal_load(&x4[start + k * 256]);
  #pragma unroll
  for (int k = 0; k < ITERS; k++) g[k] = __builtin_nontemporal_load(&t4[start + k * 256]);

  float s_xt = 0.f, s_den = 0.f;
  #pragma unroll
  for (int k = 0; k < ITERS; k++) {
    s_xt  += a[k].x * g[k].x + a[k].y * g[k].y + a[k].z * g[k].z + a[k].w * g[k].w;
    s_den += a[k].x * a[k].x + a[k].y * a[k].y + a[k].z * a[k].z + a[k].w * a[k].w
           + g[k].x * g[k].x + g[k].y * g[k].y + g[k].z * g[k].z + g[k].w * g[k].w;
  }

  // wave-64 shuffle reduction
  #pragma unroll
  for (int off = 32; off > 0; off >>= 1) {
    s_xt  += __shfl_down(s_xt, off);
    s_den += __shfl_down(s_den, off);
  }

  __shared__ float sm[8];
  const int wave = threadIdx.x >> 6;
  const int lane = threadIdx.x & 63;
  if (lane == 0) { sm[wave * 2] = s_xt; sm[wave * 2 + 1] = s_den; }
  __syncthreads();

  if (threadIdx.x == 0) {
    float2 p;
    p.x = sm[0] + sm[2] + sm[4] + sm[6];
    p.y = sm[1] + sm[3] + sm[5] + sm[7];
    part[c * NPART + b * NBX + bx] = p;   // plain store — overwrites 0xAA poison
  }
}

__global__ __launch_bounds__(256) void dice_final(
    const float2* __restrict__ part, float* __restrict__ out) {
  __shared__ float sm[8];
  float acc = 0.f;

  for (int c = 0; c < NC; c++) {
    float sx = 0.f, sd = 0.f;
    #pragma unroll
    for (int k = 0; k < NPART / 256; k++) {          // 2 iters
      float2 v = part[c * NPART + threadIdx.x + k * 256];
      sx += v.x;
      sd += v.y;
    }
    #pragma unroll
    for (int off = 32; off > 0; off >>= 1) {
      sx += __shfl_down(sx, off);
      sd += __shfl_down(sd, off);
    }
    const int wave = threadIdx.x >> 6;
    const int lane = threadIdx.x & 63;
    if (lane == 0) { sm[wave * 2] = sx; sm[wave * 2 + 1] = sd; }
    __syncthreads();
    if (threadIdx.x == 0) {
      float num = 2.f * (sm[0] + sm[2] + sm[4] + sm[6]) + EPSF;
      float den = (sm[1] + sm[3] + sm[5] + sm[7]) + EPSF;
      acc += num / den;
    }
    __syncthreads();   // sm reused next channel
  }

  if (threadIdx.x == 0) out[0] = 1.f - acc * (1.f / 3.f);
}

extern "C" void kernel_launch(void* const* d_in, const int* in_sizes, int n_in,
                              void* d_out, int out_size, void* d_ws, size_t ws_size,
                              hipStream_t stream) {
  const float* x = (const float*)d_in[0];
  const float* t = (const float*)d_in[1];
  float* out  = (float*)d_out;
  float2* part = (float2*)d_ws;   // 1536 float2 = 12 KB

  dim3 grid(NBX, NC, NB);         // 1536 blocks
  dice_partials<<<grid, 256, 0, stream>>>(x, t, part);
  dice_final<<<1, 256, 0, stream>>>(part, out);
}

// Round 8
// 114.364 us; speedup vs baseline: 1.6318x; 1.0375x over previous
//
#include <hip/hip_runtime.h>

// DiceLoss: fp32 inputs [B=16, C=3, HW=262144], scalar fp32 output.
// num[c] = 2*sum_bn(x*t); den[c] = sum_bn(x^2) + sum_bn(t^2)
// out = 1 - mean_c((num[c]+eps)/(den[c]+eps))
//
// R8 = exact revert to R3 (best: 114.7us), dropping R7's nontemporal
// loads (118.7us — NT hint traded L3 retention for L2 allocation, net
// neutral/negative). Session ledger: ~86us of dur_us is fixed harness
// reset (256MiB ws poison fill @41.5us + ~31us input restore + graph
// gaps); our two kernels ~28us (stage1 ~25us = 100.7MB at ~4 TB/s
// effective, half L3-hit per FETCH_SIZE=50MB). Tested non-levers:
// data atomics (R1, +60us), ILP 8 vs 16 loads (R2/R3, neutral), block
// count 3072 vs 1536 (neutral), single-kernel fusion w/ ticket+fence
// (R4, +72us), NT loads (R7, +4us).

#define HW 262144          // 512*512
#define NC 3
#define NB 16
#define NBX 32             // blocks per (b,c) plane — compile-time so loop unrolls
#define ITERS (HW / 4 / NBX / 256)   // 8 float4-pair loads per thread
#define NPART (NB * NBX)   // 512 partials per channel
#define EPSF 1e-5f

// ws layout: float2 partial[c*NPART + b*NBX + bx] = {sum(x*t), sum(x^2+t^2)}

__global__ __launch_bounds__(256) void dice_partials(
    const float* __restrict__ x, const float* __restrict__ t,
    float2* __restrict__ part) {
  const int bx = blockIdx.x;
  const int c  = blockIdx.y;
  const int b  = blockIdx.z;
  const size_t base = ((size_t)b * NC + c) * (size_t)HW;
  const float4* __restrict__ x4 = (const float4*)(x + base);
  const float4* __restrict__ t4 = (const float4*)(t + base);

  const int start = bx * (ITERS * 256) + threadIdx.x;

  // All 16 independent loads issued up front — max memory-level parallelism.
  float4 a[ITERS], g[ITERS];
  #pragma unroll
  for (int k = 0; k < ITERS; k++) a[k] = x4[start + k * 256];
  #pragma unroll
  for (int k = 0; k < ITERS; k++) g[k] = t4[start + k * 256];

  float s_xt = 0.f, s_den = 0.f;
  #pragma unroll
  for (int k = 0; k < ITERS; k++) {
    s_xt  += a[k].x * g[k].x + a[k].y * g[k].y + a[k].z * g[k].z + a[k].w * g[k].w;
    s_den += a[k].x * a[k].x + a[k].y * a[k].y + a[k].z * a[k].z + a[k].w * a[k].w
           + g[k].x * g[k].x + g[k].y * g[k].y + g[k].z * g[k].z + g[k].w * g[k].w;
  }

  // wave-64 shuffle reduction
  #pragma unroll
  for (int off = 32; off > 0; off >>= 1) {
    s_xt  += __shfl_down(s_xt, off);
    s_den += __shfl_down(s_den, off);
  }

  __shared__ float sm[8];
  const int wave = threadIdx.x >> 6;
  const int lane = threadIdx.x & 63;
  if (lane == 0) { sm[wave * 2] = s_xt; sm[wave * 2 + 1] = s_den; }
  __syncthreads();

  if (threadIdx.x == 0) {
    float2 p;
    p.x = sm[0] + sm[2] + sm[4] + sm[6];
    p.y = sm[1] + sm[3] + sm[5] + sm[7];
    part[c * NPART + b * NBX + bx] = p;   // plain store — overwrites 0xAA poison
  }
}

__global__ __launch_bounds__(256) void dice_final(
    const float2* __restrict__ part, float* __restrict__ out) {
  __shared__ float sm[8];
  float acc = 0.f;

  for (int c = 0; c < NC; c++) {
    float sx = 0.f, sd = 0.f;
    #pragma unroll
    for (int k = 0; k < NPART / 256; k++) {          // 2 iters
      float2 v = part[c * NPART + threadIdx.x + k * 256];
      sx += v.x;
      sd += v.y;
    }
    #pragma unroll
    for (int off = 32; off > 0; off >>= 1) {
      sx += __shfl_down(sx, off);
      sd += __shfl_down(sd, off);
    }
    const int wave = threadIdx.x >> 6;
    const int lane = threadIdx.x & 63;
    if (lane == 0) { sm[wave * 2] = sx; sm[wave * 2 + 1] = sd; }
    __syncthreads();
    if (threadIdx.x == 0) {
      float num = 2.f * (sm[0] + sm[2] + sm[4] + sm[6]) + EPSF;
      float den = (sm[1] + sm[3] + sm[5] + sm[7]) + EPSF;
      acc += num / den;
    }
    __syncthreads();   // sm reused next channel
  }

  if (threadIdx.x == 0) out[0] = 1.f - acc * (1.f / 3.f);
}

extern "C" void kernel_launch(void* const* d_in, const int* in_sizes, int n_in,
                              void* d_out, int out_size, void* d_ws, size_t ws_size,
                              hipStream_t stream) {
  const float* x = (const float*)d_in[0];
  const float* t = (const float*)d_in[1];
  float* out  = (float*)d_out;
  float2* part = (float2*)d_ws;   // 1536 float2 = 12 KB

  dim3 grid(NBX, NC, NB);         // 1536 blocks
  dice_partials<<<grid, 256, 0, stream>>>(x, t, part);
  dice_final<<<1, 256, 0, stream>>>(part, out);
}